// Round 2
// baseline (21150.536 us; speedup 1.0000x reference)
//
#include <hip/hip_runtime.h>
#include <math.h>

// ---------------- problem constants ----------------
#define BB 32768
#define LL 24
#define HH 128
#define ZZ 32

// ---------------- main-kernel geometry ----------------
#define ROWS 32          // batch rows per block
#define NTHR 256         // 4 waves
// LDS float offsets (total 15552 floats = 62.2 KB)
#define HB  0            // h state   [32][129]
#define XB  4128         // scratch A [32][129]
#define YB  8256         // scratch B [32][129]
#define S1  12384        // 1056 fl: lsb(prolog) / ph / z / bbox
#define SM2 13440        // 2112 fl: gt / inter / d2
#define LDS_TOT 15552
#define SB 129           // big stride (bank spread: (r+k)%32)
#define SS 33            // small stride

__device__ __forceinline__ float sigf(float x){ return 1.0f/(1.0f+__expf(-x)); }
__device__ __forceinline__ float tanhf_(float x){ return 2.0f/(1.0f+__expf(-2.0f*x)) - 1.0f; }

// out-slab accumulate: acc[jj] += sum_k in[r][k] * W[k][j0+jj]
template<int K, int TN>
__device__ __forceinline__ void mm_slab(const float* __restrict__ sin, int sstride, int r,
                                        const float* __restrict__ W, int ldw, int j0,
                                        float* acc)
{
  #pragma unroll 4
  for (int k = 0; k < K; ++k) {
    float a = sin[r*sstride + k];
    const float* wr = &W[k*ldw + j0];
    #pragma unroll
    for (int jj = 0; jj < TN; ++jj) acc[jj] = fmaf(a, wr[jj], acc[jj]);
  }
}

// ---------------- tiny setup kernel: per-t vectors + fused encoder weight ----------------
// ws layout (floats): vecB[24*128] @0 ; Wfuse[128*32] @3072 ; bfuse[32] @7168
__global__ void vae_pre(const float* __restrict__ cw3, const float* __restrict__ cb3,
                        const float* __restrict__ cw4, const float* __restrict__ cb4,
                        const float* __restrict__ cwo,
                        const float* __restrict__ ew2, const float* __restrict__ ew3,
                        const float* __restrict__ eb2, const float* __restrict__ eb3,
                        float* __restrict__ ws)
{
  __shared__ float t1[24][129];
  __shared__ float t2[24][129];
  const int tid = threadIdx.x;
  for (int idx = tid; idx < 24*128; idx += 256) {
    int tt = idx >> 7, j = idx & 127;
    t1[tt][j] = fmaxf(cw3[tt*HH + j] + cb3[j], 0.f);   // relu(eye@cw3+cb3) row tt
  }
  __syncthreads();
  for (int idx = tid; idx < 24*128; idx += 256) {
    int tt = idx >> 7, j = idx & 127;
    float a = cb4[j];
    for (int k = 0; k < 128; ++k) a = fmaf(t1[tt][k], cw4[k*HH + j], a);
    t2[tt][j] = fmaxf(a, 0.f);                          // i2_all[tt][j]
  }
  __syncthreads();
  for (int idx = tid; idx < 24*128; idx += 256) {       // vecB = i2_all @ cwoB
    int tt = idx >> 7, j = idx & 127;
    float a = 0.f;
    for (int k = 0; k < 128; ++k) a = fmaf(t2[tt][k], cwo[(128+k)*HH + j], a);
    ws[tt*HH + j] = a;
  }
  for (int idx = tid; idx < 128*32; idx += 256) {       // Wfuse = ew2 @ ew3[0:128]
    int k = idx >> 5, j = idx & 31;
    float a = 0.f;
    for (int kk = 0; kk < 128; ++kk) a = fmaf(ew2[k*HH + kk], ew3[kk*ZZ + j], a);
    ws[3072 + k*ZZ + j] = a;
  }
  if (tid < 32) {                                       // bfuse = eb2@ew3a + eb3
    float a = eb3[tid];
    for (int kk = 0; kk < 128; ++kk) a = fmaf(eb2[kk], ew3[kk*ZZ + tid], a);
    ws[7168 + tid] = a;
  }
}

// ---------------- main persistent kernel: 32 rows/block, 24 steps ----------------
__global__ void __launch_bounds__(NTHR, 2) vae_main(
  const float* __restrict__ ls, const float* __restrict__ bbin, const float* __restrict__ eps,
  const float* __restrict__ cw1, const float* __restrict__ cb1,
  const float* __restrict__ cw2, const float* __restrict__ cb2,
  const float* __restrict__ cw5, const float* __restrict__ cb5,
  const float* __restrict__ cwo, const float* __restrict__ cbo,
  const float* __restrict__ pw1, const float* __restrict__ pb1,
  const float* __restrict__ pwm, const float* __restrict__ pbm,
  const float* __restrict__ pwv, const float* __restrict__ pbv,
  const float* __restrict__ ew1, const float* __restrict__ eb1,
  const float* __restrict__ ew3,
  const float* __restrict__ ewm, const float* __restrict__ ebm,
  const float* __restrict__ ewv, const float* __restrict__ ebv,
  const float* __restrict__ dw1, const float* __restrict__ db1,
  const float* __restrict__ dw2, const float* __restrict__ db2,
  const float* __restrict__ dw3, const float* __restrict__ db3,
  const float* __restrict__ lk, const float* __restrict__ lr, const float* __restrict__ lb,
  const float* __restrict__ ws,
  float* __restrict__ outB, float* __restrict__ outK)
{
  __shared__ float sh[LDS_TOT];
  const int tid  = threadIdx.x;
  const int lane = tid & 63;
  const int r    = lane & 31;        // row within block
  const int half = lane >> 5;        // 0/1
  const int wv   = tid >> 6;         // wave 0..3
  const int slab = wv*2 + half;      // 0..7 column slabs
  const int rbase = blockIdx.x * ROWS;
  const int grow  = rbase + r;
  const int j0 = slab * 16;          // slab of 16 for N=128 outputs
  const int q0 = slab * 4;           // slab of 4  for N=32 outputs
  const int p0 = slab * 8;           // slab of 8  for N=64 outputs

  const float* vecB  = ws;
  const float* Wfuse = ws + 3072;
  const float* bfuse = ws + 7168;

  // ---- prologue: label_set branch folded to registers ----
  for (int idx = tid; idx < 32*24; idx += NTHR) {       // ls -> S1 as [32][25]
    int rr = idx / 24, kk = idx - rr*24;
    sh[S1 + rr*25 + kk] = ls[(rbase+rr)*LL + kk];
  }
  __syncthreads();
  {
    float acc[16];
    #pragma unroll
    for (int jj = 0; jj < 16; ++jj) acc[jj] = cb1[j0+jj];
    mm_slab<24,16>(&sh[S1], 25, r, cw1, HH, j0, acc);
    #pragma unroll
    for (int jj = 0; jj < 16; ++jj) sh[XB + r*SB + j0+jj] = fmaxf(acc[jj], 0.f);
  }
  __syncthreads();
  {
    float acc[16];
    #pragma unroll
    for (int jj = 0; jj < 16; ++jj) acc[jj] = cb2[j0+jj];
    mm_slab<128,16>(&sh[XB], SB, r, cw2, HH, j0, acc);
    #pragma unroll
    for (int jj = 0; jj < 16; ++jj) sh[YB + r*SB + j0+jj] = fmaxf(acc[jj], 0.f);
  }
  __syncthreads();
  float caReg[16];                                      // condA = i1@cwoA + cbo (register-resident)
  {
    #pragma unroll
    for (int jj = 0; jj < 16; ++jj) caReg[jj] = cbo[j0+jj];
    mm_slab<128,16>(&sh[YB], SB, r, cwo, HH, j0, caReg);
  }
  for (int idx = tid; idx < 4128; idx += NTHR) sh[HB + idx] = 0.f;   // h = 0
  float creg[16];
  #pragma unroll
  for (int jj = 0; jj < 16; ++jj) creg[jj] = 0.f;                    // c = 0
  __syncthreads();

  // ---- 24 recurrent steps ----
  for (int st = 0; st < LL; ++st) {
    // step-top prefetch: gt (bbin) and eps into registers; consumed in P2/P5.
    // Loads issue here, waitcnt lands after thousands of FMAs -> latency hidden.
    float gtreg = 0.f;
    const int prr = tid >> 2, pkk = tid & 3;            // valid when tid<128
    if (tid < 128)
      gtreg = bbin[((size_t)(rbase+prr)*LL + st)*4 + pkk];
    const size_t eb = ((size_t)grow*LL + st)*ZZ;
    float epr[4];
    #pragma unroll
    for (int q = 0; q < 4; ++q) epr[q] = eps[eb + q0 + q];

    // P1: i3 = relu(h@cw5+cb5) -> XB
    {
      float acc[16];
      #pragma unroll
      for (int jj = 0; jj < 16; ++jj) acc[jj] = cb5[j0+jj];
      mm_slab<128,16>(&sh[HB], SB, r, cw5, HH, j0, acc);
      #pragma unroll
      for (int jj = 0; jj < 16; ++jj) sh[XB + r*SB + j0+jj] = fmaxf(acc[jj], 0.f);
    }
    __syncthreads();
    // P2: cond = i3@cwoC + condA + vecB[st] -> YB ; gt -> SM2[32][5]
    {
      float acc[16];
      const float* vb = &vecB[st*HH + j0];
      #pragma unroll
      for (int jj = 0; jj < 16; ++jj) acc[jj] = caReg[jj] + vb[jj];
      mm_slab<128,16>(&sh[XB], SB, r, &cwo[256*HH], HH, j0, acc);
      #pragma unroll
      for (int jj = 0; jj < 16; ++jj) sh[YB + r*SB + j0+jj] = acc[jj];
    }
    if (tid < 128) sh[SM2 + prr*5 + pkk] = gtreg;
    __syncthreads();
    // P3: relu1 = relu(gt@ew1+eb1) -> XB ; ph = relu(cond@pw1+pb1) -> S1[32][33]
    {
      float acc[16];
      #pragma unroll
      for (int jj = 0; jj < 16; ++jj) acc[jj] = eb1[j0+jj];
      mm_slab<4,16>(&sh[SM2], 5, r, ew1, HH, j0, acc);
      #pragma unroll
      for (int jj = 0; jj < 16; ++jj) sh[XB + r*SB + j0+jj] = fmaxf(acc[jj], 0.f);
    }
    {
      float acc[4];
      #pragma unroll
      for (int q = 0; q < 4; ++q) acc[q] = pb1[q0+q];
      mm_slab<128,4>(&sh[YB], SB, r, pw1, ZZ, q0, acc);
      #pragma unroll
      for (int q = 0; q < 4; ++q) sh[S1 + r*SS + q0+q] = fmaxf(acc[q], 0.f);
    }
    __syncthreads();
    // P4: zmc,zvc (registers) ; inter = relu(relu1@Wfuse + cond@ew3b + bfuse) -> SM2[32][33]
    float zmc[4], zvc[4];
    {
      #pragma unroll
      for (int q = 0; q < 4; ++q) { zmc[q] = pbm[q0+q]; zvc[q] = pbv[q0+q]; }
      #pragma unroll 4
      for (int k = 0; k < 32; ++k) {
        float a = sh[S1 + r*SS + k];
        const float* wm = &pwm[k*ZZ + q0];
        const float* wq = &pwv[k*ZZ + q0];
        #pragma unroll
        for (int q = 0; q < 4; ++q) { zmc[q] = fmaf(a, wm[q], zmc[q]); zvc[q] = fmaf(a, wq[q], zvc[q]); }
      }
    }
    {
      float acc[4];
      #pragma unroll
      for (int q = 0; q < 4; ++q) acc[q] = bfuse[q0+q];
      mm_slab<128,4>(&sh[XB], SB, r, Wfuse, ZZ, q0, acc);
      mm_slab<128,4>(&sh[YB], SB, r, &ew3[128*ZZ], ZZ, q0, acc);
      #pragma unroll
      for (int q = 0; q < 4; ++q) sh[SM2 + r*SS + q0+q] = fmaxf(acc[q], 0.f);
    }
    __syncthreads();
    // P5: zm,zv ; kl -> global ; z -> S1[32][33]
    {
      float am[4], av[4];
      #pragma unroll
      for (int q = 0; q < 4; ++q) { am[q] = ebm[q0+q]; av[q] = ebv[q0+q]; }
      #pragma unroll 4
      for (int k = 0; k < 32; ++k) {
        float a = sh[SM2 + r*SS + k];
        const float* wm = &ewm[k*ZZ + q0];
        const float* wq = &ewv[k*ZZ + q0];
        #pragma unroll
        for (int q = 0; q < 4; ++q) { am[q] = fmaf(a, wm[q], am[q]); av[q] = fmaf(a, wq[q], av[q]); }
      }
      #pragma unroll
      for (int q = 0; q < 4; ++q) {
        float d  = am[q] - zmc[q];
        float kl = 0.5f*(zvc[q] - av[q] + (__expf(av[q]) + d*d)*__expf(-zvc[q]) - 1.0f);
        outK[eb + q0 + q] = kl;
        sh[S1 + r*SS + q0+q] = am[q] + __expf(0.5f*av[q]) * epr[q];
      }
    }
    __syncthreads();
    // P6: d1 = relu(cond@dw1a + z@dw1b + db1) -> XB
    {
      float acc[16];
      #pragma unroll
      for (int jj = 0; jj < 16; ++jj) acc[jj] = db1[j0+jj];
      mm_slab<128,16>(&sh[YB], SB, r, dw1, HH, j0, acc);
      mm_slab<32,16>(&sh[S1], SS, r, &dw1[128*HH], HH, j0, acc);
      #pragma unroll
      for (int jj = 0; jj < 16; ++jj) sh[XB + r*SB + j0+jj] = fmaxf(acc[jj], 0.f);
    }
    __syncthreads();
    // P7: d2 = relu(d1@dw2+db2) -> SM2 stride 65
    {
      float acc[8];
      #pragma unroll
      for (int p = 0; p < 8; ++p) acc[p] = db2[p0+p];
      mm_slab<128,8>(&sh[XB], SB, r, dw2, 64, p0, acc);
      #pragma unroll
      for (int p = 0; p < 8; ++p) sh[SM2 + r*65 + p0+p] = fmaxf(acc[p], 0.f);
    }
    __syncthreads();
    // P8: bbox = sigmoid(d2@dw3+db3) -> S1[32][5] + global
    if (tid < 128) {
      int rr = tid >> 2, j = tid & 3;
      float acc = db3[j];
      #pragma unroll 4
      for (int k = 0; k < 64; ++k) acc = fmaf(sh[SM2 + rr*65 + k], dw3[k*4 + j], acc);
      float bx = sigf(acc);
      sh[S1 + rr*5 + j] = bx;
      outB[((size_t)(rbase+rr)*LL + st)*4 + j] = bx;
    }
    __syncthreads();
    // P9a: gates = lk[st]+lb + bbox@lk[24:28] + h@lr
    float ga[4][16];
    {
      #pragma unroll
      for (int g = 0; g < 4; ++g) {
        #pragma unroll
        for (int jj = 0; jj < 16; ++jj)
          ga[g][jj] = lb[g*HH + j0+jj] + lk[st*512 + g*HH + j0+jj];
      }
      #pragma unroll 2
      for (int k = 0; k < 128; ++k) {
        float a = sh[HB + r*SB + k];
        #pragma unroll
        for (int g = 0; g < 4; ++g) {
          const float* wr = &lr[k*512 + g*HH + j0];
          #pragma unroll
          for (int jj = 0; jj < 16; ++jj) ga[g][jj] = fmaf(a, wr[jj], ga[g][jj]);
        }
      }
      #pragma unroll
      for (int k = 0; k < 4; ++k) {
        float a = sh[S1 + r*5 + k];
        #pragma unroll
        for (int g = 0; g < 4; ++g) {
          const float* wr = &lk[(24+k)*512 + g*HH + j0];
          #pragma unroll
          for (int jj = 0; jj < 16; ++jj) ga[g][jj] = fmaf(a, wr[jj], ga[g][jj]);
        }
      }
    }
    __syncthreads();   // all reads of old h done before overwrite
    // P9b: LSTM elementwise (keras i,f,c,o), write h
    {
      #pragma unroll
      for (int jj = 0; jj < 16; ++jj) {
        float gi = sigf(ga[0][jj]);
        float gf = sigf(ga[1][jj]);
        float gg = tanhf_(ga[2][jj]);
        float go = sigf(ga[3][jj]);
        float cn = fmaf(gf, creg[jj], gi*gg);
        creg[jj] = cn;
        sh[HB + r*SB + j0+jj] = go * tanhf_(cn);
      }
    }
    __syncthreads();
  }
}

extern "C" void kernel_launch(void* const* d_in, const int* in_sizes, int n_in,
                              void* d_out, int out_size, void* d_ws, size_t ws_size,
                              hipStream_t stream)
{
  const float* ls  = (const float*)d_in[0];
  const float* bbin= (const float*)d_in[1];
  const float* eps = (const float*)d_in[2];
  const float* cw1=(const float*)d_in[3];  const float* cb1=(const float*)d_in[4];
  const float* cw2=(const float*)d_in[5];  const float* cb2=(const float*)d_in[6];
  const float* cw3=(const float*)d_in[7];  const float* cb3=(const float*)d_in[8];
  const float* cw4=(const float*)d_in[9];  const float* cb4=(const float*)d_in[10];
  const float* cw5=(const float*)d_in[11]; const float* cb5=(const float*)d_in[12];
  const float* cwo=(const float*)d_in[13]; const float* cbo=(const float*)d_in[14];
  const float* pw1=(const float*)d_in[15]; const float* pb1=(const float*)d_in[16];
  const float* pwm=(const float*)d_in[17]; const float* pbm=(const float*)d_in[18];
  const float* pwv=(const float*)d_in[19]; const float* pbv=(const float*)d_in[20];
  const float* ew1=(const float*)d_in[21]; const float* eb1=(const float*)d_in[22];
  const float* ew2=(const float*)d_in[23]; const float* eb2=(const float*)d_in[24];
  const float* ew3=(const float*)d_in[25]; const float* eb3=(const float*)d_in[26];
  const float* ewm=(const float*)d_in[27]; const float* ebm=(const float*)d_in[28];
  const float* ewv=(const float*)d_in[29]; const float* ebv=(const float*)d_in[30];
  const float* dw1=(const float*)d_in[31]; const float* db1=(const float*)d_in[32];
  const float* dw2=(const float*)d_in[33]; const float* db2=(const float*)d_in[34];
  const float* dw3=(const float*)d_in[35]; const float* db3=(const float*)d_in[36];
  const float* lk =(const float*)d_in[37]; const float* lr =(const float*)d_in[38];
  const float* lb =(const float*)d_in[39];

  float* ws   = (float*)d_ws;                       // needs only 28.8 KB
  float* outB = (float*)d_out;                      // [B,L,4]
  float* outK = outB + (size_t)BB*LL*4;             // [B,L,32]

  vae_pre<<<dim3(1), dim3(256), 0, stream>>>(cw3,cb3,cw4,cb4,cwo,ew2,ew3,eb2,eb3,ws);
  vae_main<<<dim3(BB/ROWS), dim3(NTHR), 0, stream>>>(
      ls,bbin,eps,cw1,cb1,cw2,cb2,cw5,cb5,cwo,cbo,
      pw1,pb1,pwm,pbm,pwv,pbv,ew1,eb1,ew3,ewm,ebm,ewv,ebv,
      dw1,db1,dw2,db2,dw3,db3,lk,lr,lb,ws,outB,outK);
}

// Round 3
// 5508.128 us; speedup vs baseline: 3.8399x; 3.8399x over previous
//
#include <hip/hip_runtime.h>
#include <math.h>

// ---------------- problem constants ----------------
#define BB 32768
#define LL 24
#define HH 128
#define ZZ 32

// ---------------- geometry ----------------
#define ROWS 64
#define NTHR 512
#define NBLK (BB/ROWS)        // 512 blocks, 1/CU (157KB LDS), 2 generations

// ---------------- LDS float offsets ----------------
#define XB0 0                 // h       [128c][64r] swizzled (8192)
#define XB1 8192              // scratch [128c][64r] swizzled
#define XB2 16384             // cond    [128c][64r] swizzled
#define WSO 24576             // weight stage buffer (8704 floats = 34KB)
#define SAO 33280             // small act A: ph -> z   [32][64] (2048)
#define SBO 35328             // small act B: inter     [32][64] (2048)  (SA..SB = d2 [64][64])
#define GTO 37376             // gt   [4][64] (256)
#define BXO 37632             // bbox [4][64] (256)
#define PERM 37888            // biases etc (1440)
#define LDS_FL 39328
#define LDS_BYTES (LDS_FL*4)  // 157312 < 163840

// PERM sub-offsets (floats)
#define P_CB5 0
#define P_EB1 128
#define P_DB1 256
#define P_DB2 384
#define P_DB3 448
#define P_PB1 452
#define P_PBM 484
#define P_PBV 516
#define P_EBM 548
#define P_EBV 580
#define P_BFU 612
#define P_LB  644
#define P_DW3 1156

__device__ __forceinline__ float sigf(float x){ return 1.0f/(1.0f+__expf(-x)); }
__device__ __forceinline__ float tanhf_(float x){ return 2.0f/(1.0f+__expf(-2.0f*x)) - 1.0f; }

// cooperative contiguous stage: nfl multiple of 4
__device__ __forceinline__ void stageW(const float* __restrict__ g, float* __restrict__ l,
                                       int nfl, int tid){
  for (int i = tid*4; i < nfl; i += NTHR*4) {
    const float4 v = *(const float4*)(g + i);
    *(float4*)(l + i) = v;
  }
}
// cooperative strided stage: rows x 128 cols from row-major [.,ldsrc]
__device__ __forceinline__ void stageChunk(const float* __restrict__ g, float* __restrict__ l,
                                           int rows, int ldsrc, int tid){
  for (int i = tid; i < rows*32; i += NTHR) {
    const int rr = i >> 5, cb = (i & 31)*4;
    *(float4*)(l + rr*128 + cb) = *(const float4*)(g + rr*ldsrc + cb);
  }
}

// swizzled xbuf dword offset: col j, 4-row-group rg. write 4-way conflict, reads broadcast.
__device__ __forceinline__ int xoff4(int j, int rg){ return (j<<6) + (((rg ^ (j>>2)) & 15)<<2); }

// acc[4][4] += x[kbase..kbase+KC)[r0..r0+3] * Ws[0..KC)[c0..c0+3]
template<int KC, int LDW, bool SWZ>
__device__ __forceinline__ void mac4x4(const float* __restrict__ xb, const float* __restrict__ Ws,
                                       int kbase, int rg, int c0, float (&acc)[4][4])
{
  #pragma unroll 4
  for (int k = 0; k < KC; ++k) {
    const int kk = kbase + k;
    const float4 xv = *(const float4*)&xb[ SWZ ? xoff4(kk, rg) : ((kk<<6) + (rg<<2)) ];
    const float4 wv = *(const float4*)&Ws[k*LDW + c0];
    const float xa[4] = {xv.x, xv.y, xv.z, xv.w};
    const float wa[4] = {wv.x, wv.y, wv.z, wv.w};
    #pragma unroll
    for (int ri = 0; ri < 4; ++ri)
      #pragma unroll
      for (int ci = 0; ci < 4; ++ci)
        acc[ri][ci] = fmaf(xa[ri], wa[ci], acc[ri][ci]);
  }
}

// small-N phase: acc[4] += x[k][rS] * Ws[k][c0s..+3]
template<int KC, int LDW, bool SWZ>
__device__ __forceinline__ void macS(const float* __restrict__ xb, const float* __restrict__ Ws,
                                     int rS, int c0s, float (&acc)[4])
{
  const int rg = rS >> 2, rl = rS & 3;
  #pragma unroll 4
  for (int k = 0; k < KC; ++k) {
    const float a = xb[ SWZ ? (xoff4(k, rg) + rl) : (k*64 + rS) ];
    const float4 wv = *(const float4*)&Ws[k*LDW + c0s];
    acc[0] = fmaf(a, wv.x, acc[0]); acc[1] = fmaf(a, wv.y, acc[1]);
    acc[2] = fmaf(a, wv.z, acc[2]); acc[3] = fmaf(a, wv.w, acc[3]);
  }
}

template<bool RELU>
__device__ __forceinline__ void stTile(float* __restrict__ xb, int rg, int c0, const float (&acc)[4][4]){
  #pragma unroll
  for (int ci = 0; ci < 4; ++ci) {
    const int j = c0 + ci;
    float4 v;
    v.x = acc[0][ci]; v.y = acc[1][ci]; v.z = acc[2][ci]; v.w = acc[3][ci];
    if (RELU) { v.x=fmaxf(v.x,0.f); v.y=fmaxf(v.y,0.f); v.z=fmaxf(v.z,0.f); v.w=fmaxf(v.w,0.f); }
    *(float4*)&xb[xoff4(j, rg)] = v;
  }
}

__device__ __forceinline__ void initB4(const float* __restrict__ b, int c0, float (&acc)[4][4]){
  const float4 bv = *(const float4*)&b[c0];
  #pragma unroll
  for (int ri = 0; ri < 4; ++ri){ acc[ri][0]=bv.x; acc[ri][1]=bv.y; acc[ri][2]=bv.z; acc[ri][3]=bv.w; }
}

// ---------------- setup kernel: vecB[24][128], Wfuse[128][32], bfuse[32] into ws ----------------
__global__ void vae_pre(const float* __restrict__ cw3, const float* __restrict__ cb3,
                        const float* __restrict__ cw4, const float* __restrict__ cb4,
                        const float* __restrict__ cwo,
                        const float* __restrict__ ew2, const float* __restrict__ ew3,
                        const float* __restrict__ eb2, const float* __restrict__ eb3,
                        float* __restrict__ ws)
{
  __shared__ float t1[24][129];
  __shared__ float t2[24][129];
  const int tid = threadIdx.x;
  for (int idx = tid; idx < 24*128; idx += 256) {
    int tt = idx >> 7, j = idx & 127;
    t1[tt][j] = fmaxf(cw3[tt*HH + j] + cb3[j], 0.f);
  }
  __syncthreads();
  for (int idx = tid; idx < 24*128; idx += 256) {
    int tt = idx >> 7, j = idx & 127;
    float a = cb4[j];
    for (int k = 0; k < 128; ++k) a = fmaf(t1[tt][k], cw4[k*HH + j], a);
    t2[tt][j] = fmaxf(a, 0.f);
  }
  __syncthreads();
  for (int idx = tid; idx < 24*128; idx += 256) {
    int tt = idx >> 7, j = idx & 127;
    float a = 0.f;
    for (int k = 0; k < 128; ++k) a = fmaf(t2[tt][k], cwo[(128+k)*HH + j], a);
    ws[tt*HH + j] = a;
  }
  for (int idx = tid; idx < 128*32; idx += 256) {
    int k = idx >> 5, j = idx & 31;
    float a = 0.f;
    for (int kk = 0; kk < 128; ++kk) a = fmaf(ew2[k*HH + kk], ew3[kk*ZZ + j], a);
    ws[3072 + k*ZZ + j] = a;
  }
  if (tid < 32) {
    float a = eb3[tid];
    for (int kk = 0; kk < 128; ++kk) a = fmaf(eb2[kk], ew3[kk*ZZ + tid], a);
    ws[7168 + tid] = a;
  }
}

// ---------------- main kernel ----------------
__global__ void __launch_bounds__(NTHR, 2) vae_main(
  const float* __restrict__ ls, const float* __restrict__ bbin, const float* __restrict__ eps,
  const float* __restrict__ cw1, const float* __restrict__ cb1,
  const float* __restrict__ cw2, const float* __restrict__ cb2,
  const float* __restrict__ cw5, const float* __restrict__ cb5,
  const float* __restrict__ cwo, const float* __restrict__ cbo,
  const float* __restrict__ pw1, const float* __restrict__ pb1,
  const float* __restrict__ pwm, const float* __restrict__ pbm,
  const float* __restrict__ pwv, const float* __restrict__ pbv,
  const float* __restrict__ ew1, const float* __restrict__ eb1,
  const float* __restrict__ ew3,
  const float* __restrict__ ewm, const float* __restrict__ ebm,
  const float* __restrict__ ewv, const float* __restrict__ ebv,
  const float* __restrict__ dw1, const float* __restrict__ db1,
  const float* __restrict__ dw2, const float* __restrict__ db2,
  const float* __restrict__ dw3, const float* __restrict__ db3,
  const float* __restrict__ lk, const float* __restrict__ lr, const float* __restrict__ lb,
  const float* __restrict__ ws,
  float* __restrict__ outB, float* __restrict__ outK)
{
  extern __shared__ float sh[];
  const int tid  = threadIdx.x;
  const int colg = tid & 31;         // big-phase: 32 col-groups x 4 cols
  const int rowg = tid >> 5;         // 16 row-groups x 4 rows
  const int c0   = colg * 4;
  const int rS   = tid & 63;         // small-phase: row
  const int cq   = tid >> 6;         // small-phase: wave = col-quad
  const int c0s  = cq * 4;
  const int rbase = blockIdx.x * ROWS;

  // ---------------- prologue ----------------
  for (int i = tid; i < 8192; i += NTHR) sh[XB0 + i] = 0.f;   // h = 0
  for (int i = tid; i < 128; i += NTHR) {
    sh[PERM+P_CB5+i] = cb5[i]; sh[PERM+P_EB1+i] = eb1[i]; sh[PERM+P_DB1+i] = db1[i];
  }
  if (tid < 64) sh[PERM+P_DB2+tid] = db2[tid];
  if (tid < 4)  sh[PERM+P_DB3+tid] = db3[tid];
  if (tid < 32) {
    sh[PERM+P_PB1+tid] = pb1[tid]; sh[PERM+P_PBM+tid] = pbm[tid]; sh[PERM+P_PBV+tid] = pbv[tid];
    sh[PERM+P_EBM+tid] = ebm[tid]; sh[PERM+P_EBV+tid] = ebv[tid]; sh[PERM+P_BFU+tid] = ws[7168+tid];
  }
  sh[PERM+P_LB+tid] = lb[tid];
  for (int i = tid; i < 256; i += NTHR) sh[PERM+P_DW3+i] = dw3[i];
  for (int i = tid; i < 24*64; i += NTHR) {                   // lsb [24][64] in SA region
    int rr = i & 63, kk = i >> 6;
    sh[SAO + kk*64 + rr] = ls[(size_t)(rbase+rr)*LL + kk];
  }
  stageW(cw1, &sh[WSO], 3072, tid);
  __syncthreads();
  float caReg[4][4];
  {
    float a[4][4]; initB4(cb1, c0, a);                        // t1 = relu(ls@cw1+cb1)
    mac4x4<24,128,false>(&sh[SAO], &sh[WSO], 0, rowg, c0, a);
    stTile<true>(&sh[XB1], rowg, c0, a);
  }
  __syncthreads();
  stageW(cw2, &sh[WSO], 8192, tid); __syncthreads();
  float i1a[4][4]; initB4(cb2, c0, i1a);
  mac4x4<64,128,true>(&sh[XB1], &sh[WSO], 0, rowg, c0, i1a); __syncthreads();
  stageW(&cw2[64*HH], &sh[WSO], 8192, tid); __syncthreads();
  mac4x4<64,128,true>(&sh[XB1], &sh[WSO], 64, rowg, c0, i1a); // i1
  stTile<true>(&sh[XB2], rowg, c0, i1a);
  __syncthreads();
  stageW(cwo, &sh[WSO], 8192, tid); __syncthreads();
  initB4(cbo, c0, caReg);                                     // condA = i1@cwoA + cbo
  mac4x4<64,128,true>(&sh[XB2], &sh[WSO], 0, rowg, c0, caReg); __syncthreads();
  stageW(&cwo[64*HH], &sh[WSO], 8192, tid); __syncthreads();
  mac4x4<64,128,true>(&sh[XB2], &sh[WSO], 64, rowg, c0, caReg);
  __syncthreads();

  float creg[4][4];
  #pragma unroll
  for (int ri=0; ri<4; ++ri)
    #pragma unroll
    for (int ci=0; ci<4; ++ci) creg[ri][ci] = 0.f;

  // ---------------- 24 steps ----------------
  for (int st = 0; st < LL; ++st) {
    // step-top prefetches (consumed much later -> latency hidden)
    float gtreg = 0.f;
    if (tid < 256) gtreg = bbin[(((size_t)rbase + rS)*LL + st)*4 + cq];
    const float4 epv = *(const float4*)&eps[(((size_t)rbase + rS)*LL + st)*ZZ + c0s];
    float lkr_[4][4];
    #pragma unroll
    for (int g = 0; g < 4; ++g) {
      const float4 t = *(const float4*)&lk[st*512 + g*128 + c0];
      lkr_[g][0]=t.x; lkr_[g][1]=t.y; lkr_[g][2]=t.z; lkr_[g][3]=t.w;
    }
    const float4 vbv = *(const float4*)&ws[st*HH + c0];
    const float vbr[4] = {vbv.x, vbv.y, vbv.z, vbv.w};

    // S1: cw5 kh0 + gt->LDS
    stageW(cw5, &sh[WSO], 8192, tid);
    if (tid < 256) sh[GTO + cq*64 + rS] = gtreg;
    __syncthreads();
    // C1/C2: P1 i3 = relu(h@cw5+cb5) -> XB1
    float a1[4][4]; initB4(&sh[PERM+P_CB5], c0, a1);
    mac4x4<64,128,true>(&sh[XB0], &sh[WSO], 0, rowg, c0, a1);
    __syncthreads();
    stageW(&cw5[64*HH], &sh[WSO], 8192, tid); __syncthreads();
    mac4x4<64,128,true>(&sh[XB0], &sh[WSO], 64, rowg, c0, a1);
    stTile<true>(&sh[XB1], rowg, c0, a1);
    __syncthreads();
    // P2: cond = i3@cwoC + condA + vecB[st] -> XB2
    stageW(&cwo[256*HH], &sh[WSO], 8192, tid); __syncthreads();
    float a2[4][4];
    #pragma unroll
    for (int ri=0; ri<4; ++ri)
      #pragma unroll
      for (int ci=0; ci<4; ++ci) a2[ri][ci] = caReg[ri][ci] + vbr[ci];
    mac4x4<64,128,true>(&sh[XB1], &sh[WSO], 0, rowg, c0, a2);
    __syncthreads();
    stageW(&cwo[(256+64)*HH], &sh[WSO], 8192, tid); __syncthreads();
    mac4x4<64,128,true>(&sh[XB1], &sh[WSO], 64, rowg, c0, a2);
    stTile<false>(&sh[XB2], rowg, c0, a2);
    __syncthreads();
    // S5: pw1 @0, ew1 @4096, pwm @4608, pwv @5632
    stageW(pw1, &sh[WSO], 4096, tid);
    stageW(ew1, &sh[WSO+4096], 512, tid);
    stageW(pwm, &sh[WSO+4608], 1024, tid);
    stageW(pwv, &sh[WSO+5632], 1024, tid);
    __syncthreads();
    // C5: P3a relu1 = relu(gt@ew1+eb1) -> XB1 ; P3b ph = relu(cond@pw1+pb1) -> SA
    {
      float a3[4][4]; initB4(&sh[PERM+P_EB1], c0, a3);
      mac4x4<4,128,false>(&sh[GTO], &sh[WSO+4096], 0, rowg, c0, a3);
      stTile<true>(&sh[XB1], rowg, c0, a3);
      const float4 pb = *(const float4*)&sh[PERM+P_PB1+c0s];
      float p3[4] = {pb.x, pb.y, pb.z, pb.w};
      macS<128,32,true>(&sh[XB2], &sh[WSO], rS, c0s, p3);
      #pragma unroll
      for (int i = 0; i < 4; ++i) sh[SAO + (c0s+i)*64 + rS] = fmaxf(p3[i], 0.f);
    }
    __syncthreads();
    // C6: zmc, zvc (regs)
    float zmc[4], zvc[4];
    {
      const float4 bm = *(const float4*)&sh[PERM+P_PBM+c0s];
      const float4 bq = *(const float4*)&sh[PERM+P_PBV+c0s];
      zmc[0]=bm.x; zmc[1]=bm.y; zmc[2]=bm.z; zmc[3]=bm.w;
      zvc[0]=bq.x; zvc[1]=bq.y; zvc[2]=bq.z; zvc[3]=bq.w;
      macS<32,32,false>(&sh[SAO], &sh[WSO+4608], rS, c0s, zmc);
      macS<32,32,false>(&sh[SAO], &sh[WSO+5632], rS, c0s, zvc);
    }
    __syncthreads();
    // S6 + C7: inter = relu(relu1@Wfuse + cond@ew3b + bfuse) -> SB
    stageW(&ws[3072], &sh[WSO], 4096, tid);
    stageW(&ew3[128*ZZ], &sh[WSO+4096], 4096, tid);
    __syncthreads();
    {
      const float4 bf = *(const float4*)&sh[PERM+P_BFU+c0s];
      float iv[4] = {bf.x, bf.y, bf.z, bf.w};
      macS<128,32,true>(&sh[XB1], &sh[WSO],      rS, c0s, iv);
      macS<128,32,true>(&sh[XB2], &sh[WSO+4096], rS, c0s, iv);
      #pragma unroll
      for (int i = 0; i < 4; ++i) sh[SBO + (c0s+i)*64 + rS] = fmaxf(iv[i], 0.f);
    }
    __syncthreads();
    // S7 + C8: zm/zv, kl -> outK, z -> SA
    stageW(ewm, &sh[WSO], 1024, tid);
    stageW(ewv, &sh[WSO+1024], 1024, tid);
    __syncthreads();
    {
      const float4 bm = *(const float4*)&sh[PERM+P_EBM+c0s];
      const float4 bq = *(const float4*)&sh[PERM+P_EBV+c0s];
      float zm[4] = {bm.x, bm.y, bm.z, bm.w};
      float zv[4] = {bq.x, bq.y, bq.z, bq.w};
      macS<32,32,false>(&sh[SBO], &sh[WSO],      rS, c0s, zm);
      macS<32,32,false>(&sh[SBO], &sh[WSO+1024], rS, c0s, zv);
      const float epr[4] = {epv.x, epv.y, epv.z, epv.w};
      float klv[4];
      #pragma unroll
      for (int i = 0; i < 4; ++i) {
        const float d = zm[i] - zmc[i];
        klv[i] = 0.5f*(zvc[i] - zv[i] + (__expf(zv[i]) + d*d)*__expf(-zvc[i]) - 1.0f);
        sh[SAO + (c0s+i)*64 + rS] = zm[i] + __expf(0.5f*zv[i]) * epr[i];
      }
      float4 ko; ko.x=klv[0]; ko.y=klv[1]; ko.z=klv[2]; ko.w=klv[3];
      *(float4*)&outK[(((size_t)rbase + rS)*LL + st)*ZZ + c0s] = ko;
    }
    __syncthreads();
    // P6: d1 = relu(cond@dw1a + z@dw1b + db1) -> XB1
    stageW(dw1, &sh[WSO], 8192, tid); __syncthreads();
    float a6[4][4]; initB4(&sh[PERM+P_DB1], c0, a6);
    mac4x4<64,128,true>(&sh[XB2], &sh[WSO], 0, rowg, c0, a6);
    __syncthreads();
    stageW(&dw1[64*HH], &sh[WSO], 8192, tid); __syncthreads();
    mac4x4<64,128,true>(&sh[XB2], &sh[WSO], 64, rowg, c0, a6);
    __syncthreads();
    stageW(&dw1[128*HH], &sh[WSO], 4096, tid); __syncthreads();
    mac4x4<32,128,false>(&sh[SAO], &sh[WSO], 0, rowg, c0, a6);
    stTile<true>(&sh[XB1], rowg, c0, a6);
    __syncthreads();
    // P7: d2 = relu(d1@dw2+db2) -> SD ([64][64] over SA+SB)
    stageW(dw2, &sh[WSO], 8192, tid); __syncthreads();
    {
      const int cg7 = tid & 15, rg7 = tid >> 4;
      const int c07 = cg7*4, r07 = rg7*2;
      float a7[2][4];
      const float4 bv = *(const float4*)&sh[PERM+P_DB2 + c07];
      a7[0][0]=bv.x; a7[0][1]=bv.y; a7[0][2]=bv.z; a7[0][3]=bv.w;
      a7[1][0]=bv.x; a7[1][1]=bv.y; a7[1][2]=bv.z; a7[1][3]=bv.w;
      #pragma unroll 4
      for (int k = 0; k < 128; ++k) {
        const float2 xv = *(const float2*)&sh[XB1 + xoff4(k, rg7>>1) + (rg7&1)*2];
        const float4 wv = *(const float4*)&sh[WSO + k*64 + c07];
        a7[0][0]=fmaf(xv.x,wv.x,a7[0][0]); a7[0][1]=fmaf(xv.x,wv.y,a7[0][1]);
        a7[0][2]=fmaf(xv.x,wv.z,a7[0][2]); a7[0][3]=fmaf(xv.x,wv.w,a7[0][3]);
        a7[1][0]=fmaf(xv.y,wv.x,a7[1][0]); a7[1][1]=fmaf(xv.y,wv.y,a7[1][1]);
        a7[1][2]=fmaf(xv.y,wv.z,a7[1][2]); a7[1][3]=fmaf(xv.y,wv.w,a7[1][3]);
      }
      #pragma unroll
      for (int ci = 0; ci < 4; ++ci) {
        float2 v; v.x = fmaxf(a7[0][ci], 0.f); v.y = fmaxf(a7[1][ci], 0.f);
        *(float2*)&sh[SAO + (c07+ci)*64 + r07] = v;
      }
    }
    __syncthreads();
    // P8: bbox = sigmoid(d2@dw3+db3) -> BX + outB
    if (tid < 256) {
      const int c8 = cq;  // 0..3
      float acc = sh[PERM+P_DB3 + c8];
      #pragma unroll 4
      for (int k = 0; k < 64; ++k)
        acc = fmaf(sh[SAO + k*64 + rS], sh[PERM+P_DW3 + k*4 + c8], acc);
      const float bx = sigf(acc);
      sh[BXO + c8*64 + rS] = bx;
      outB[(((size_t)rbase + rS)*LL + st)*4 + c8] = bx;
    }
    __syncthreads();
    // P9: LSTM gates i,f,c,o — one acc, staged lr chunks
    float ti[4][4];   // sig(i) stash
    #pragma unroll
    for (int g = 0; g < 4; ++g) {
      float ag[4][4];
      #pragma unroll
      for (int ri=0; ri<4; ++ri)
        #pragma unroll
        for (int ci=0; ci<4; ++ci)
          ag[ri][ci] = sh[PERM+P_LB + g*128 + c0 + ci] + lkr_[g][ci];
      stageChunk(&lr[g*128], &sh[WSO], 64, 512, tid);
      stageChunk(&lk[24*512 + g*128], &sh[WSO+8192], 4, 512, tid);
      __syncthreads();
      mac4x4<64,128,true>(&sh[XB0], &sh[WSO], 0, rowg, c0, ag);
      __syncthreads();
      stageChunk(&lr[64*512 + g*128], &sh[WSO], 64, 512, tid);
      __syncthreads();
      mac4x4<64,128,true>(&sh[XB0], &sh[WSO], 64, rowg, c0, ag);
      mac4x4<4,128,false>(&sh[BXO], &sh[WSO+8192], 0, rowg, c0, ag);
      __syncthreads();   // all reads of h/WS done
      if (g == 0) {           // i
        #pragma unroll
        for (int ri=0; ri<4; ++ri)
          #pragma unroll
          for (int ci=0; ci<4; ++ci) ti[ri][ci] = sigf(ag[ri][ci]);
      } else if (g == 1) {    // f
        #pragma unroll
        for (int ri=0; ri<4; ++ri)
          #pragma unroll
          for (int ci=0; ci<4; ++ci) creg[ri][ci] *= sigf(ag[ri][ci]);
      } else if (g == 2) {    // c
        #pragma unroll
        for (int ri=0; ri<4; ++ri)
          #pragma unroll
          for (int ci=0; ci<4; ++ci) creg[ri][ci] = fmaf(ti[ri][ci], tanhf_(ag[ri][ci]), creg[ri][ci]);
      } else {                // o -> h write (after barrier above: safe)
        #pragma unroll
        for (int ci = 0; ci < 4; ++ci) {
          const int j = c0 + ci;
          float4 hv;
          hv.x = sigf(ag[0][ci]) * tanhf_(creg[0][ci]);
          hv.y = sigf(ag[1][ci]) * tanhf_(creg[1][ci]);
          hv.z = sigf(ag[2][ci]) * tanhf_(creg[2][ci]);
          hv.w = sigf(ag[3][ci]) * tanhf_(creg[3][ci]);
          *(float4*)&sh[XB0 + xoff4(j, rowg)] = hv;
        }
      }
    }
    // next iteration's first stage + its barrier orders XB0 writes before P1 reads
  }
}

extern "C" void kernel_launch(void* const* d_in, const int* in_sizes, int n_in,
                              void* d_out, int out_size, void* d_ws, size_t ws_size,
                              hipStream_t stream)
{
  const float* ls  = (const float*)d_in[0];
  const float* bbin= (const float*)d_in[1];
  const float* eps = (const float*)d_in[2];
  const float* cw1=(const float*)d_in[3];  const float* cb1=(const float*)d_in[4];
  const float* cw2=(const float*)d_in[5];  const float* cb2=(const float*)d_in[6];
  const float* cw3=(const float*)d_in[7];  const float* cb3=(const float*)d_in[8];
  const float* cw4=(const float*)d_in[9];  const float* cb4=(const float*)d_in[10];
  const float* cw5=(const float*)d_in[11]; const float* cb5=(const float*)d_in[12];
  const float* cwo=(const float*)d_in[13]; const float* cbo=(const float*)d_in[14];
  const float* pw1=(const float*)d_in[15]; const float* pb1=(const float*)d_in[16];
  const float* pwm=(const float*)d_in[17]; const float* pbm=(const float*)d_in[18];
  const float* pwv=(const float*)d_in[19]; const float* pbv=(const float*)d_in[20];
  const float* ew1=(const float*)d_in[21]; const float* eb1=(const float*)d_in[22];
  const float* ew2=(const float*)d_in[23]; const float* eb2=(const float*)d_in[24];
  const float* ew3=(const float*)d_in[25]; const float* eb3=(const float*)d_in[26];
  const float* ewm=(const float*)d_in[27]; const float* ebm=(const float*)d_in[28];
  const float* ewv=(const float*)d_in[29]; const float* ebv=(const float*)d_in[30];
  const float* dw1=(const float*)d_in[31]; const float* db1=(const float*)d_in[32];
  const float* dw2=(const float*)d_in[33]; const float* db2=(const float*)d_in[34];
  const float* dw3=(const float*)d_in[35]; const float* db3=(const float*)d_in[36];
  const float* lk =(const float*)d_in[37]; const float* lr =(const float*)d_in[38];
  const float* lb =(const float*)d_in[39];

  float* ws   = (float*)d_ws;
  float* outB = (float*)d_out;
  float* outK = outB + (size_t)BB*LL*4;

  hipFuncSetAttribute((const void*)vae_main, hipFuncAttributeMaxDynamicSharedMemorySize, LDS_BYTES);

  vae_pre<<<dim3(1), dim3(256), 0, stream>>>(cw3,cb3,cw4,cb4,cwo,ew2,ew3,eb2,eb3,ws);
  vae_main<<<dim3(NBLK), dim3(NTHR), LDS_BYTES, stream>>>(
      ls,bbin,eps,cw1,cb1,cw2,cb2,cw5,cb5,cwo,cbo,
      pw1,pb1,pwm,pbm,pwv,pbv,ew1,eb1,ew3,ewm,ebm,ewv,ebv,
      dw1,db1,dw2,db2,dw3,db3,lk,lr,lb,ws,outB,outK);
}

// Round 4
// 3249.235 us; speedup vs baseline: 6.5094x; 1.6952x over previous
//
#include <hip/hip_runtime.h>
#include <math.h>

// ---------------- problem constants ----------------
#define BB 32768
#define LL 24
#define HH 128
#define ZZ 32
#define ROWS 64
#define NTHR 512
#define NBLK (BB/ROWS)

typedef __attribute__((ext_vector_type(8))) short bf16x8;
typedef __attribute__((ext_vector_type(4))) float f32x4;
#define MFMA16(a,b,c) __builtin_amdgcn_mfma_f32_16x16x32_bf16(a,b,c,0,0,0)

// ---------------- LDS byte offsets (total 161936 <= 163840) ----------------
#define STG   0        // 32768: staged B-weight [128][128] bf16 (XOR swizzled)
#define HB    32768    // 16384: h   [64][128] bf16 XOR
#define CONDB 49152    // 16384: cond(bf16) / i1(prologue)
#define AB    65536    // 16384: i3 / relu1 / d1 bf16 XOR
#define ZB    81920    // 5120:  z [64 rows][stride 80B] bf16 (K=32)
#define DW1BT 87040    // 10240: dw1b^T [128][stride 80B] bf16 resident
#define PW1T  97280    // 8192:  pw1^T [32][128] bf16 XOR resident
#define WFUT  105472   // 8192:  Wfuse^T resident
#define EW3BT 113664   // 8192:  ew3b^T resident
#define MVW   121856   // 16384: pwm,pwv,ewm,ewv f32 [32][32] each
#define SAB   138240   // 17408: SA=ph [32col][68row] f32; SB=+8704 inter; D2 overlay [64][68]
#define GTB   155648   // 1088:  gt [4][68] f32
#define BXB   156736   // 1088:  bbox [4][68] f32
#define PERMB 157824   // 4112:  ew1 f32@0, eb1@2048, dw3@2560, db3@3584, pbm@3600, pbv@3728, ebm@3856, ebv@3984
#define LDS_BYTES 161936

// ---------------- ws (global scratch) byte offsets ----------------
#define W_VECB 0           // f32 [24][128]
#define W_BFU  12288       // f32 [32]
#define WB     12416
#define W_CW2T  (WB+0)       // [128][128] bf16 packed (all *T are [N][K])
#define W_CWOAT (WB+32768)
#define W_CW5T  (WB+65536)
#define W_CWOCT (WB+98304)
#define W_DW1AT (WB+131072)
#define W_DW2T  (WB+163840)  // [64][128]
#define W_LRT   (WB+180224)  // [512][128]
#define W_PW1T  (WB+311296)  // [32][128]
#define W_WFUT  (WB+319488)
#define W_EW3BT (WB+327680)
#define W_DW1BT (WB+335872)  // [128][32]

__device__ __forceinline__ float sigf(float x){ return 1.0f/(1.0f+__expf(-x)); }
__device__ __forceinline__ float tanhf_(float x){ return 2.0f/(1.0f+__expf(-2.0f*x)) - 1.0f; }
__device__ __forceinline__ ushort f2b(float f){
  union{float f; unsigned u;} x; x.f = f;
  unsigned r = x.u + 0x7FFFu + ((x.u>>16)&1u);
  return (ushort)(r>>16);
}

// A/B fragment load from XOR-swizzled [idx][128] bf16 buffer (256B row stride)
__device__ __forceinline__ bf16x8 ldfrag(const char* sm, int base, int idx, int kk, int lch){
  int b = idx*256 + kk*64 + lch*16;
  b ^= (idx&7)<<4;
  return *(const bf16x8*)(sm + base + b);
}
// fragment load from stride-80B K<=32 buffer (no swizzle; pad-based spread)
__device__ __forceinline__ bf16x8 ldfragP(const char* sm, int base, int idx, int lch){
  return *(const bf16x8*)(sm + base + idx*80 + lch*16);
}
// scalar bf16 store into XOR-swizzled A-buffer
__device__ __forceinline__ void stb16(char* sm, int base, int row, int col, ushort v){
  int b = row*256 + col*2;
  b ^= (row&7)<<4;
  *(ushort*)(sm + base + b) = v;
}
// paired bf16 store (col even)
__device__ __forceinline__ void stb32(char* sm, int base, int row, int col, unsigned v){
  int b = row*256 + col*2;
  b ^= (row&7)<<4;
  *(unsigned*)(sm + base + b) = v;
}

// staged-weight copy helpers: issue loads early (regs), write late (XOR layout)
template<int NR>
__device__ __forceinline__ void stg_issue(const char* __restrict__ src, int tid, uint4* r){
  #pragma unroll
  for (int i = 0; i < NR*16/NTHR; ++i)
    r[i] = *(const uint4*)(src + (tid + i*NTHR)*16);
}
template<int NR>
__device__ __forceinline__ void stg_write(char* sm, int tid, const uint4* r){
  #pragma unroll
  for (int i = 0; i < NR*16/NTHR; ++i){
    int idx = tid + i*NTHR;
    int row = idx >> 4, ch = idx & 15;
    *(uint4*)(sm + STG + row*256 + ((ch*16) ^ ((row&7)<<4))) = r[i];
  }
}

// ---------------- setup kernel ----------------
// block 0: vecB/Wfuse^T/bfuse chain. blocks 1..41: weight transposes (f32 [K][N] -> bf16 [N][K])
__global__ void vae_pre(const float* __restrict__ cw2,
                        const float* __restrict__ cw3, const float* __restrict__ cb3,
                        const float* __restrict__ cw4, const float* __restrict__ cb4,
                        const float* __restrict__ cw5,
                        const float* __restrict__ cwo,
                        const float* __restrict__ pw1,
                        const float* __restrict__ ew2, const float* __restrict__ ew3,
                        const float* __restrict__ eb2, const float* __restrict__ eb3,
                        const float* __restrict__ dw1, const float* __restrict__ dw2,
                        const float* __restrict__ lr,
                        char* __restrict__ ws)
{
  const int tid = threadIdx.x;
  if (blockIdx.x == 0) {
    __shared__ float t1[24][129];
    __shared__ float t2[24][129];
    for (int idx = tid; idx < 24*128; idx += 256) {
      int tt = idx >> 7, j = idx & 127;
      t1[tt][j] = fmaxf(cw3[tt*HH + j] + cb3[j], 0.f);
    }
    __syncthreads();
    for (int idx = tid; idx < 24*128; idx += 256) {
      int tt = idx >> 7, j = idx & 127;
      float a = cb4[j];
      for (int k = 0; k < 128; ++k) a = fmaf(t1[tt][k], cw4[k*HH + j], a);
      t2[tt][j] = fmaxf(a, 0.f);
    }
    __syncthreads();
    float* vecB = (float*)(ws + W_VECB);
    for (int idx = tid; idx < 24*128; idx += 256) {
      int tt = idx >> 7, j = idx & 127;
      float a = 0.f;
      for (int k = 0; k < 128; ++k) a = fmaf(t2[tt][k], cwo[(128+k)*HH + j], a);
      vecB[tt*HH + j] = a;
    }
    ushort* wfut = (ushort*)(ws + W_WFUT);       // [32][128]: wfut[n*128+k] = Wfuse[k][n]
    for (int idx = tid; idx < 128*32; idx += 256) {
      int k = idx >> 5, n = idx & 31;
      float a = 0.f;
      for (int kk = 0; kk < 128; ++kk) a = fmaf(ew2[k*HH + kk], ew3[kk*ZZ + n], a);
      wfut[n*128 + k] = f2b(a);
    }
    if (tid < 32) {
      float a = eb3[tid];
      for (int kk = 0; kk < 128; ++kk) a = fmaf(eb2[kk], ew3[kk*ZZ + tid], a);
      *(float*)(ws + W_BFU + tid*4) = a;
    }
  } else {
    int u = blockIdx.x - 1;   // 0..40, each = 4096 dst elems
    const float* src; char* dst; int K, N, uo;
    if      (u < 4)  { src = cw2;            dst = ws+W_CW2T;  K=128; N=128; uo = u;    }
    else if (u < 8)  { src = cwo;            dst = ws+W_CWOAT; K=128; N=128; uo = u-4;  }
    else if (u < 12) { src = cw5;            dst = ws+W_CW5T;  K=128; N=128; uo = u-8;  }
    else if (u < 16) { src = cwo + 256*128;  dst = ws+W_CWOCT; K=128; N=128; uo = u-12; }
    else if (u < 20) { src = dw1;            dst = ws+W_DW1AT; K=128; N=128; uo = u-16; }
    else if (u < 22) { src = dw2;            dst = ws+W_DW2T;  K=128; N=64;  uo = u-20; }
    else if (u < 38) { src = lr;             dst = ws+W_LRT;   K=128; N=512; uo = u-22; }
    else if (u == 38){ src = pw1;            dst = ws+W_PW1T;  K=128; N=32;  uo = 0;    }
    else if (u == 39){ src = ew3 + 128*32;   dst = ws+W_EW3BT; K=128; N=32;  uo = 0;    }
    else             { src = dw1 + 128*128;  dst = ws+W_DW1BT; K=32;  N=128; uo = 0;    }
    ushort* d = (ushort*)dst;
    for (int e = uo*4096 + tid; e < uo*4096 + 4096; e += 256) {
      int n = e / K, k = e - n*K;
      d[e] = f2b(src[k*N + n]);
    }
  }
}

// ---------------- main kernel ----------------
__global__ void __launch_bounds__(NTHR, 2) vae_main(
  const float* __restrict__ ls, const float* __restrict__ bbin, const float* __restrict__ eps,
  const float* __restrict__ cw1, const float* __restrict__ cb1, const float* __restrict__ cb2,
  const float* __restrict__ cb5, const float* __restrict__ cbo,
  const float* __restrict__ pb1, const float* __restrict__ pbm, const float* __restrict__ pbv,
  const float* __restrict__ pwm, const float* __restrict__ pwv,
  const float* __restrict__ ew1, const float* __restrict__ eb1,
  const float* __restrict__ ewm, const float* __restrict__ ebm,
  const float* __restrict__ ewv, const float* __restrict__ ebv,
  const float* __restrict__ db1, const float* __restrict__ db2,
  const float* __restrict__ dw3, const float* __restrict__ db3,
  const float* __restrict__ lk, const float* __restrict__ lb,
  const char* __restrict__ ws,
  float* __restrict__ outB, float* __restrict__ outK)
{
  extern __shared__ char sm[];
  const int tid = threadIdx.x;
  const int lane = tid & 63;
  const int wv   = tid >> 6;
  const int l15  = lane & 15;
  const int lch  = lane >> 4;
  // big-N (=128) mapping
  const int rt   = wv & 3;            // row tile (rows rt*16..+15)
  const int cg   = wv >> 2;           // col half (0/1): cols cg*64 + ct*16 + l15
  // small-N (=32) mapping
  const int ctS  = wv >> 2;           // 0/1
  const int colS = ctS*16 + l15;      // 0..31
  // P7 (N=64)
  const int c7b  = (wv>>2)*32;
  // P9: unit column
  const int ju   = wv*16 + l15;       // 0..127
  // fp32 small-phase mapping
  const int rS   = tid & 63;
  const int cq   = tid >> 6;          // 0..7
  const int c0s  = cq * 4;
  const int rbase = blockIdx.x * ROWS;

  const float* vecB = (const float*)(ws + W_VECB);

  // ---------------- prologue: resident LDS + bias regs ----------------
  for (int i = tid; i < 16384/16; i += NTHR)           // zero hb (1024 chunks)
    *(uint4*)(sm + HB + i*16) = (uint4){0,0,0,0};
  // resident B-weights [32][128] XOR
  {
    const char* srcs[3] = { ws+W_PW1T, ws+W_WFUT, ws+W_EW3BT };
    const int dsts[3] = { PW1T, WFUT, EW3BT };
    #pragma unroll
    for (int s = 0; s < 3; ++s)
      for (int i = tid; i < 512; i += NTHR) {
        int row = i >> 4, ch = i & 15;
        *(uint4*)(sm + dsts[s] + row*256 + ((ch*16) ^ ((row&7)<<4))) =
            *(const uint4*)(srcs[s] + i*16);
      }
  }
  for (int i = tid; i < 512; i += NTHR) {              // dw1bt [128][80B]
    int row = i >> 2, ch = i & 3;
    *(uint4*)(sm + DW1BT + row*80 + ch*16) = *(const uint4*)(ws + W_DW1BT + row*64 + ch*16);
  }
  for (int i = tid; i < 4096; i += NTHR) {             // MVW f32
    int w = i >> 10, j = i & 1023;
    const float* s = (w==0)?pwm:(w==1)?pwv:(w==2)?ewm:ewv;
    ((float*)(sm + MVW))[i] = s[j];
  }
  {
    float* P = (float*)(sm + PERMB);
    for (int i = tid; i < 512; i += NTHR) P[i] = ew1[i];
    for (int i = tid; i < 128; i += NTHR) P[512 + i] = eb1[i];
    for (int i = tid; i < 256; i += NTHR) P[640 + i] = dw3[i];
    if (tid < 4)  P[896 + tid] = db3[tid];
    if (tid < 32) { P[900+tid] = pbm[tid]; P[932+tid] = pbv[tid]; P[964+tid] = ebm[tid]; P[996+tid] = ebv[tid]; }
  }
  // ls -> SA [24][68] f32
  for (int i = tid; i < 24*64; i += NTHR) {
    int k = i >> 6, rr = i & 63;
    *(float*)(sm + SAB + k*272 + rr*4) = ls[(size_t)(rbase+rr)*LL + k];
  }
  // bias registers
  float cb5r[4], db1r[4], cb2r[4], cbor[4];
  #pragma unroll
  for (int ct = 0; ct < 4; ++ct) {
    int c = cg*64 + ct*16 + l15;
    cb5r[ct] = cb5[c]; db1r[ct] = db1[c]; cb2r[ct] = cb2[c]; cbor[ct] = cbo[c];
  }
  float db2r[2]; db2r[0] = db2[c7b + l15]; db2r[1] = db2[c7b + 16 + l15];
  const float pb1r = pb1[colS];
  const float bfr  = *(const float*)(ws + W_BFU + colS*4);
  float lbr[4], lkbr[4][4];
  #pragma unroll
  for (int g = 0; g < 4; ++g) {
    lbr[g] = lb[g*128 + ju];
    #pragma unroll
    for (int k = 0; k < 4; ++k) lkbr[k][g] = lk[(24+k)*512 + g*128 + ju];
  }
  f32x4 creg[4];
  #pragma unroll
  for (int i = 0; i < 4; ++i) creg[i] = (f32x4){0.f,0.f,0.f,0.f};

  uint4 sreg[4];
  stg_issue<128>(ws + W_CW2T, tid, sreg);
  __syncthreads();

  // T1 = relu(ls@cw1+cb1) -> AB (fp32, K=24)
  {
    const int r3 = tid >> 3, cb = (tid & 7) * 16;
    float a3[16];
    #pragma unroll
    for (int c = 0; c < 16; ++c) a3[c] = cb1[cb + c];
    for (int k = 0; k < 24; ++k) {
      float g = *(const float*)(sm + SAB + k*272 + r3*4);
      #pragma unroll
      for (int c = 0; c < 16; ++c) a3[c] = fmaf(g, cw1[k*128 + cb + c], a3[c]);
    }
    #pragma unroll
    for (int c = 0; c < 16; c += 2) {
      unsigned v = (unsigned)f2b(fmaxf(a3[c],0.f)) | ((unsigned)f2b(fmaxf(a3[c+1],0.f)) << 16);
      stb32(sm, AB, r3, cb + c, v);
    }
  }
  __syncthreads();
  stg_write<128>(sm, tid, sreg);            // cw2t
  stg_issue<128>(ws + W_CWOAT, tid, sreg);
  __syncthreads();
  // i1 = relu(T1@cw2t + cb2) -> CONDB
  {
    f32x4 o[4];
    #pragma unroll
    for (int ct = 0; ct < 4; ++ct) o[ct] = (f32x4){cb2r[ct],cb2r[ct],cb2r[ct],cb2r[ct]};
    #pragma unroll
    for (int kk = 0; kk < 4; ++kk) {
      bf16x8 av = ldfrag(sm, AB, rt*16+l15, kk, lch);
      #pragma unroll
      for (int ct = 0; ct < 4; ++ct)
        o[ct] = MFMA16(av, ldfrag(sm, STG, cg*64+ct*16+l15, kk, lch), o[ct]);
    }
    #pragma unroll
    for (int ct = 0; ct < 4; ++ct)
      #pragma unroll
      for (int r = 0; r < 4; ++r)
        stb16(sm, CONDB, rt*16+lch*4+r, cg*64+ct*16+l15, f2b(fmaxf(o[ct][r],0.f)));
  }
  __syncthreads();
  stg_write<128>(sm, tid, sreg);            // cwoAt
  stg_issue<128>(ws + W_CW5T, tid, sreg);
  __syncthreads();
  // caF = i1@cwoAt + cbo (register frags)
  f32x4 caF[4];
  #pragma unroll
  for (int ct = 0; ct < 4; ++ct) caF[ct] = (f32x4){cbor[ct],cbor[ct],cbor[ct],cbor[ct]};
  #pragma unroll
  for (int kk = 0; kk < 4; ++kk) {
    bf16x8 av = ldfrag(sm, CONDB, rt*16+l15, kk, lch);
    #pragma unroll
    for (int ct = 0; ct < 4; ++ct)
      caF[ct] = MFMA16(av, ldfrag(sm, STG, cg*64+ct*16+l15, kk, lch), caF[ct]);
  }

  // ---------------- 24 steps ----------------
  for (int st = 0; st < LL; ++st) {
    // per-step register prefetches
    float gtreg = 0.f;
    if (tid < 256) gtreg = bbin[(((size_t)rbase + rS)*LL + st)*4 + cq];
    const f32x4 epv = *(const f32x4*)&eps[(((size_t)rbase + rS)*LL + st)*ZZ + c0s];
    float lkr[4];
    #pragma unroll
    for (int g = 0; g < 4; ++g) lkr[g] = lk[st*512 + g*128 + ju];
    float vbr[4];
    #pragma unroll
    for (int ct = 0; ct < 4; ++ct) vbr[ct] = vecB[st*128 + cg*64 + ct*16 + l15];

    __syncthreads();                          // (a) prev h-writes visible, STG free
    stg_write<128>(sm, tid, sreg);            // cw5t
    stg_issue<128>(ws + W_CWOCT, tid, sreg);
    if (tid < 256) *(float*)(sm + GTB + cq*272 + rS*4) = gtreg;
    __syncthreads();                          // (b)
    // P1: i3 = relu(h@cw5 + cb5) -> AB
    {
      f32x4 o[4];
      #pragma unroll
      for (int ct = 0; ct < 4; ++ct) o[ct] = (f32x4){cb5r[ct],cb5r[ct],cb5r[ct],cb5r[ct]};
      #pragma unroll
      for (int kk = 0; kk < 4; ++kk) {
        bf16x8 av = ldfrag(sm, HB, rt*16+l15, kk, lch);
        #pragma unroll
        for (int ct = 0; ct < 4; ++ct)
          o[ct] = MFMA16(av, ldfrag(sm, STG, cg*64+ct*16+l15, kk, lch), o[ct]);
      }
      #pragma unroll
      for (int ct = 0; ct < 4; ++ct)
        #pragma unroll
        for (int r = 0; r < 4; ++r)
          stb16(sm, AB, rt*16+lch*4+r, cg*64+ct*16+l15, f2b(fmaxf(o[ct][r],0.f)));
    }
    __syncthreads();                          // (c)
    stg_write<128>(sm, tid, sreg);            // cwoCt
    stg_issue<128>(ws + W_DW1AT, tid, sreg);
    __syncthreads();                          // (d)
    // P2: cond = i3@cwoC + caF + vecB -> CONDB
    {
      f32x4 o[4];
      #pragma unroll
      for (int ct = 0; ct < 4; ++ct) {
        o[ct] = caF[ct];
        #pragma unroll
        for (int r = 0; r < 4; ++r) o[ct][r] += vbr[ct];
      }
      #pragma unroll
      for (int kk = 0; kk < 4; ++kk) {
        bf16x8 av = ldfrag(sm, AB, rt*16+l15, kk, lch);
        #pragma unroll
        for (int ct = 0; ct < 4; ++ct)
          o[ct] = MFMA16(av, ldfrag(sm, STG, cg*64+ct*16+l15, kk, lch), o[ct]);
      }
      #pragma unroll
      for (int ct = 0; ct < 4; ++ct)
        #pragma unroll
        for (int r = 0; r < 4; ++r)
          stb16(sm, CONDB, rt*16+lch*4+r, cg*64+ct*16+l15, f2b(o[ct][r]));
    }
    __syncthreads();                          // (e)
    stg_write<128>(sm, tid, sreg);            // dw1at
    stg_issue<64>(ws + W_DW2T, tid, sreg);
    // P3a: relu1 = relu(gt@ew1 + eb1) -> AB (fp32, K=4)
    {
      const float* P = (const float*)(sm + PERMB);
      const int r3 = tid >> 3, cb = (tid & 7) * 16;
      float a3[16];
      #pragma unroll
      for (int c = 0; c < 16; ++c) a3[c] = P[512 + cb + c];
      #pragma unroll
      for (int k = 0; k < 4; ++k) {
        float g = *(const float*)(sm + GTB + k*272 + r3*4);
        #pragma unroll
        for (int c = 0; c < 16; ++c) a3[c] = fmaf(g, P[k*128 + cb + c], a3[c]);
      }
      #pragma unroll
      for (int c = 0; c < 16; c += 2) {
        unsigned v = (unsigned)f2b(fmaxf(a3[c],0.f)) | ((unsigned)f2b(fmaxf(a3[c+1],0.f)) << 16);
        stb32(sm, AB, r3, cb + c, v);
      }
    }
    // C5b: ph = relu(cond@pw1 + pb1) -> SA
    {
      f32x4 ph = (f32x4){pb1r,pb1r,pb1r,pb1r};
      #pragma unroll
      for (int kk = 0; kk < 4; ++kk)
        ph = MFMA16(ldfrag(sm, CONDB, rt*16+l15, kk, lch),
                    ldfrag(sm, PW1T, colS, kk, lch), ph);
      f32x4 v;
      #pragma unroll
      for (int r = 0; r < 4; ++r) v[r] = fmaxf(ph[r], 0.f);
      *(f32x4*)(sm + SAB + colS*272 + (rt*16+lch*4)*4) = v;
    }
    __syncthreads();                          // (f)
    // C7: inter = relu(relu1@Wfuse + cond@ew3b + bfuse) -> SB
    {
      f32x4 iv = (f32x4){bfr,bfr,bfr,bfr};
      #pragma unroll
      for (int kk = 0; kk < 4; ++kk)
        iv = MFMA16(ldfrag(sm, AB, rt*16+l15, kk, lch),
                    ldfrag(sm, WFUT, colS, kk, lch), iv);
      #pragma unroll
      for (int kk = 0; kk < 4; ++kk)
        iv = MFMA16(ldfrag(sm, CONDB, rt*16+l15, kk, lch),
                    ldfrag(sm, EW3BT, colS, kk, lch), iv);
      f32x4 v;
      #pragma unroll
      for (int r = 0; r < 4; ++r) v[r] = fmaxf(iv[r], 0.f);
      *(f32x4*)(sm + SAB + 8704 + colS*272 + (rt*16+lch*4)*4) = v;
    }
    // C6: zmc,zvc (fp32 regs)
    float zmc[4], zvc[4];
    {
      const float* P = (const float*)(sm + PERMB);
      #pragma unroll
      for (int i = 0; i < 4; ++i) { zmc[i] = P[900 + c0s + i]; zvc[i] = P[932 + c0s + i]; }
      #pragma unroll 8
      for (int k = 0; k < 32; ++k) {
        float a = *(const float*)(sm + SAB + k*272 + rS*4);
        f32x4 wm = *(const f32x4*)(sm + MVW + k*128 + c0s*4);
        f32x4 wq = *(const f32x4*)(sm + MVW + 4096 + k*128 + c0s*4);
        #pragma unroll
        for (int i = 0; i < 4; ++i) { zmc[i] = fmaf(a, wm[i], zmc[i]); zvc[i] = fmaf(a, wq[i], zvc[i]); }
      }
    }
    __syncthreads();                          // (g)
    // C8: zm/zv, kl -> outK, z -> ZB
    {
      const float* P = (const float*)(sm + PERMB);
      float zm[4], zv[4];
      #pragma unroll
      for (int i = 0; i < 4; ++i) { zm[i] = P[964 + c0s + i]; zv[i] = P[996 + c0s + i]; }
      #pragma unroll 8
      for (int k = 0; k < 32; ++k) {
        float a = *(const float*)(sm + SAB + 8704 + k*272 + rS*4);
        f32x4 wm = *(const f32x4*)(sm + MVW + 8192 + k*128 + c0s*4);
        f32x4 wq = *(const f32x4*)(sm + MVW + 12288 + k*128 + c0s*4);
        #pragma unroll
        for (int i = 0; i < 4; ++i) { zm[i] = fmaf(a, wm[i], zm[i]); zv[i] = fmaf(a, wq[i], zv[i]); }
      }
      f32x4 ko; unsigned zp[2];
      #pragma unroll
      for (int i = 0; i < 4; ++i) {
        float d = zm[i] - zmc[i];
        ko[i] = 0.5f*(zvc[i] - zv[i] + (__expf(zv[i]) + d*d)*__expf(-zvc[i]) - 1.0f);
        float zval = zm[i] + __expf(0.5f*zv[i]) * epv[i];
        ushort h = f2b(zval);
        if ((i&1)==0) zp[i>>1] = h; else zp[i>>1] |= ((unsigned)h)<<16;
      }
      *(f32x4*)&outK[(((size_t)rbase + rS)*LL + st)*ZZ + c0s] = ko;
      *(uint2*)(sm + ZB + rS*80 + c0s*2) = make_uint2(zp[0], zp[1]);
    }
    __syncthreads();                          // (h) zb ready, dw1at staged
    // P6: d1 = relu(cond@dw1a + z@dw1b + db1) -> AB
    {
      f32x4 o[4];
      #pragma unroll
      for (int ct = 0; ct < 4; ++ct) o[ct] = (f32x4){db1r[ct],db1r[ct],db1r[ct],db1r[ct]};
      #pragma unroll
      for (int kk = 0; kk < 4; ++kk) {
        bf16x8 av = ldfrag(sm, CONDB, rt*16+l15, kk, lch);
        #pragma unroll
        for (int ct = 0; ct < 4; ++ct)
          o[ct] = MFMA16(av, ldfrag(sm, STG, cg*64+ct*16+l15, kk, lch), o[ct]);
      }
      bf16x8 azv = ldfragP(sm, ZB, rt*16+l15, lch);
      #pragma unroll
      for (int ct = 0; ct < 4; ++ct)
        o[ct] = MFMA16(azv, ldfragP(sm, DW1BT, cg*64+ct*16+l15, lch), o[ct]);
      #pragma unroll
      for (int ct = 0; ct < 4; ++ct)
        #pragma unroll
        for (int r = 0; r < 4; ++r)
          stb16(sm, AB, rt*16+lch*4+r, cg*64+ct*16+l15, f2b(fmaxf(o[ct][r],0.f)));
    }
    __syncthreads();                          // (i)
    stg_write<64>(sm, tid, sreg);             // dw2t
    stg_issue<128>(ws + W_LRT, tid, sreg);    // lr gate 0
    __syncthreads();                          // (j)
    // P7: d2 = relu(d1@dw2 + db2) -> D2 (f32, overlays SA/SB)
    {
      f32x4 d2[2];
      #pragma unroll
      for (int p = 0; p < 2; ++p) d2[p] = (f32x4){db2r[p],db2r[p],db2r[p],db2r[p]};
      #pragma unroll
      for (int kk = 0; kk < 4; ++kk) {
        bf16x8 av = ldfrag(sm, AB, rt*16+l15, kk, lch);
        #pragma unroll
        for (int p = 0; p < 2; ++p)
          d2[p] = MFMA16(av, ldfrag(sm, STG, c7b + p*16 + l15, kk, lch), d2[p]);
      }
      #pragma unroll
      for (int p = 0; p < 2; ++p) {
        f32x4 v;
        #pragma unroll
        for (int r = 0; r < 4; ++r) v[r] = fmaxf(d2[p][r], 0.f);
        *(f32x4*)(sm + SAB + (c7b + p*16 + l15)*272 + (rt*16+lch*4)*4) = v;
      }
    }
    __syncthreads();                          // (k)
    stg_write<128>(sm, tid, sreg);            // lr g0
    stg_issue<128>(ws + W_LRT + 32768, tid, sreg);
    // P8: bbox = sigmoid(d2@dw3 + db3) -> BX + outB (fp32)
    if (tid < 256) {
      const float* P = (const float*)(sm + PERMB);
      const int c8 = tid >> 6;
      float a = P[896 + c8];
      #pragma unroll 8
      for (int k = 0; k < 64; ++k)
        a = fmaf(*(const float*)(sm + SAB + k*272 + rS*4), P[640 + k*4 + c8], a);
      float bx = sigf(a);
      *(float*)(sm + BXB + c8*272 + rS*4) = bx;
      outB[(((size_t)rbase + rS)*LL + st)*4 + c8] = bx;
    }
    __syncthreads();                          // (l) lr0 + BX ready
    // P9: gates (keras i,f,c,o), per-gate staged lr, accumulators persist
    f32x4 a90[4], a91[4], a92[4], a93[4];
    #pragma unroll
    for (int r = 0; r < 4; ++r) {
      a90[r] = (f32x4){lbr[0]+lkr[0],lbr[0]+lkr[0],lbr[0]+lkr[0],lbr[0]+lkr[0]};
      a91[r] = (f32x4){lbr[1]+lkr[1],lbr[1]+lkr[1],lbr[1]+lkr[1],lbr[1]+lkr[1]};
      a92[r] = (f32x4){lbr[2]+lkr[2],lbr[2]+lkr[2],lbr[2]+lkr[2],lbr[2]+lkr[2]};
      a93[r] = (f32x4){lbr[3]+lkr[3],lbr[3]+lkr[3],lbr[3]+lkr[3],lbr[3]+lkr[3]};
    }
    #pragma unroll
    for (int kk = 0; kk < 4; ++kk) {          // gate 0
      bf16x8 bv = ldfrag(sm, STG, ju, kk, lch);
      #pragma unroll
      for (int r = 0; r < 4; ++r)
        a90[r] = MFMA16(ldfrag(sm, HB, r*16+l15, kk, lch), bv, a90[r]);
    }
    __syncthreads();
    stg_write<128>(sm, tid, sreg);            // lr g1
    stg_issue<128>(ws + W_LRT + 65536, tid, sreg);
    __syncthreads();
    #pragma unroll
    for (int kk = 0; kk < 4; ++kk) {          // gate 1
      bf16x8 bv = ldfrag(sm, STG, ju, kk, lch);
      #pragma unroll
      for (int r = 0; r < 4; ++r)
        a91[r] = MFMA16(ldfrag(sm, HB, r*16+l15, kk, lch), bv, a91[r]);
    }
    __syncthreads();
    stg_write<128>(sm, tid, sreg);            // lr g2
    stg_issue<128>(ws + W_LRT + 98304, tid, sreg);
    __syncthreads();
    #pragma unroll
    for (int kk = 0; kk < 4; ++kk) {          // gate 2
      bf16x8 bv = ldfrag(sm, STG, ju, kk, lch);
      #pragma unroll
      for (int r = 0; r < 4; ++r)
        a92[r] = MFMA16(ldfrag(sm, HB, r*16+l15, kk, lch), bv, a92[r]);
    }
    __syncthreads();
    stg_write<128>(sm, tid, sreg);            // lr g3
    stg_issue<128>(ws + W_CW5T, tid, sreg);   // next step's cw5t
    __syncthreads();
    #pragma unroll
    for (int kk = 0; kk < 4; ++kk) {          // gate 3
      bf16x8 bv = ldfrag(sm, STG, ju, kk, lch);
      #pragma unroll
      for (int r = 0; r < 4; ++r)
        a93[r] = MFMA16(ldfrag(sm, HB, r*16+l15, kk, lch), bv, a93[r]);
    }
    // bbox tail (fp32, K=4) into all gates
    #pragma unroll
    for (int rr = 0; rr < 4; ++rr)
      #pragma unroll
      for (int r = 0; r < 4; ++r) {
        const int row = rr*16 + lch*4 + r;
        #pragma unroll
        for (int k = 0; k < 4; ++k) {
          float bx = *(const float*)(sm + BXB + k*272 + row*4);
          a90[rr][r] = fmaf(bx, lkbr[k][0], a90[rr][r]);
          a91[rr][r] = fmaf(bx, lkbr[k][1], a91[rr][r]);
          a92[rr][r] = fmaf(bx, lkbr[k][2], a92[rr][r]);
          a93[rr][r] = fmaf(bx, lkbr[k][3], a93[rr][r]);
        }
      }
    __syncthreads();                          // (m) all HB reads done
    // LSTM elementwise; h -> HB
    #pragma unroll
    for (int rr = 0; rr < 4; ++rr)
      #pragma unroll
      for (int r = 0; r < 4; ++r) {
        float gi = sigf(a90[rr][r]);
        float gf = sigf(a91[rr][r]);
        float gg = tanhf_(a92[rr][r]);
        float go = sigf(a93[rr][r]);
        float cn = fmaf(gf, creg[rr][r], gi*gg);
        creg[rr][r] = cn;
        stb16(sm, HB, rr*16 + lch*4 + r, ju, f2b(go * tanhf_(cn)));
      }
  }
}

extern "C" void kernel_launch(void* const* d_in, const int* in_sizes, int n_in,
                              void* d_out, int out_size, void* d_ws, size_t ws_size,
                              hipStream_t stream)
{
  const float* ls  = (const float*)d_in[0];
  const float* bbin= (const float*)d_in[1];
  const float* eps = (const float*)d_in[2];
  const float* cw1=(const float*)d_in[3];  const float* cb1=(const float*)d_in[4];
  const float* cw2=(const float*)d_in[5];  const float* cb2=(const float*)d_in[6];
  const float* cw3=(const float*)d_in[7];  const float* cb3=(const float*)d_in[8];
  const float* cw4=(const float*)d_in[9];  const float* cb4=(const float*)d_in[10];
  const float* cw5=(const float*)d_in[11]; const float* cb5=(const float*)d_in[12];
  const float* cwo=(const float*)d_in[13]; const float* cbo=(const float*)d_in[14];
  const float* pw1=(const float*)d_in[15]; const float* pb1=(const float*)d_in[16];
  const float* pwm=(const float*)d_in[17]; const float* pbm=(const float*)d_in[18];
  const float* pwv=(const float*)d_in[19]; const float* pbv=(const float*)d_in[20];
  const float* ew1=(const float*)d_in[21]; const float* eb1=(const float*)d_in[22];
  const float* ew2=(const float*)d_in[23]; const float* eb2=(const float*)d_in[24];
  const float* ew3=(const float*)d_in[25]; const float* eb3=(const float*)d_in[26];
  const float* ewm=(const float*)d_in[27]; const float* ebm=(const float*)d_in[28];
  const float* ewv=(const float*)d_in[29]; const float* ebv=(const float*)d_in[30];
  const float* dw1=(const float*)d_in[31]; const float* db1=(const float*)d_in[32];
  const float* dw2=(const float*)d_in[33]; const float* db2=(const float*)d_in[34];
  const float* dw3=(const float*)d_in[35]; const float* db3=(const float*)d_in[36];
  const float* lk =(const float*)d_in[37]; const float* lr =(const float*)d_in[38];
  const float* lb =(const float*)d_in[39];

  char* ws = (char*)d_ws;                  // needs ~348 KB
  float* outB = (float*)d_out;
  float* outK = outB + (size_t)BB*LL*4;

  hipFuncSetAttribute((const void*)vae_main, hipFuncAttributeMaxDynamicSharedMemorySize, LDS_BYTES);

  vae_pre<<<dim3(42), dim3(256), 0, stream>>>(cw2, cw3, cb3, cw4, cb4, cw5, cwo, pw1,
                                              ew2, ew3, eb2, eb3, dw1, dw2, lr, ws);
  vae_main<<<dim3(NBLK), dim3(NTHR), LDS_BYTES, stream>>>(
      ls, bbin, eps, cw1, cb1, cb2, cb5, cbo,
      pb1, pbm, pbv, pwm, pwv, ew1, eb1, ewm, ebm, ewv, ebv,
      db1, db2, dw3, db3, lk, lb, ws, outB, outK);
}